// Round 9
// baseline (582.831 us; speedup 1.0000x reference)
//
#include <hip/hip_runtime.h>
#include <hip/hip_bf16.h>

#define HID 128
#define DIN 192      // N_FEAT + NUM_SEM
#define NCH 65536
#define NE  1048576

typedef __bf16 bfrag __attribute__((ext_vector_type(8)));
typedef float  ffrag __attribute__((ext_vector_type(4)));
typedef long   lfrag2 __attribute__((ext_vector_type(2)));

static __device__ __forceinline__ __bf16 f2bf(float x) { return (__bf16)x; }
static __device__ __forceinline__ unsigned pk2(float a, float b) {
    __bf16 b0 = f2bf(a), b1 = f2bf(b);
    return (unsigned)*(unsigned short*)&b0 | ((unsigned)*(unsigned short*)&b1 << 16);
}
// f32 -> OCP e4m3 byte (gfx950 hw cvt)
static __device__ __forceinline__ unsigned char f2q(float x) {
    return (unsigned char)(__builtin_amdgcn_cvt_pk_fp8_f32(x, x, 0, false) & 0xff);
}

struct FragsQ { long d[4]; long ef; };

// Vectorized B-fragment staging: chunk c = ((kt*8+u)*64+lane); 8 strided
// (L2-hot) fp32 loads -> one ds_write_b128.
static __device__ __forceinline__ void stage_wfrag(
    __bf16* Wl, const float* W, int rowoff, int chunks, int t)
{
    for (int c = t; c < chunks; c += 256) {
        int lane = c & 63, u = (c >> 6) & 7, kt = c >> 9;
        int k0 = kt * 32 + ((lane >> 4) << 3), h = u * 16 + (lane & 15);
        const float* src = W + (size_t)(rowoff + k0) * 128 + h;
        bfrag f;
        #pragma unroll
        for (int j = 0; j < 8; ++j) f[j] = f2bf(src[(size_t)j * 128]);
        *(bfrag*)(&Wl[(size_t)c << 3]) = f;
    }
}

// ---------------------------------------------------------------------------
// Child encoder FUSED with edge histogram.
// ---------------------------------------------------------------------------
__global__ __launch_bounds__(256) void k_childhist(
    const float* __restrict__ cf, const float* __restrict__ exists,
    const float* __restrict__ Wc, const float* __restrict__ bc,
    __bf16* __restrict__ xA, unsigned int* __restrict__ pmax,
    const int* __restrict__ eidx, int* __restrict__ deg)
{
    if (blockIdx.x >= 1024) {
        const int base = (blockIdx.x - 1024) * 1024 + threadIdx.x;
        #pragma unroll
        for (int k = 0; k < 4; ++k)
            atomicAdd(&deg[eidx[2 * (base + k * 256)]], 1);
        return;
    }

    __shared__ __bf16 Wl[6 * 8 * 64 * 8];   // 48 KB, B-fragment-swizzled
    __shared__ float  bl[HID];
    __shared__ unsigned int cm[HID];
    const int t = threadIdx.x;

    stage_wfrag(Wl, Wc, 0, 3072, t);        // DIN*HID/8 chunks
    for (int idx = t; idx < HID; idx += 256) { bl[idx] = bc[idx]; cm[idx] = 0u; }
    __syncthreads();

    const int wave = t >> 6, lane = t & 63;
    const int m = lane & 15, quad = lane >> 4;

    const int tile = blockIdx.x * 4 + wave;   // 1024 blocks -> 4096 tiles
    const int r0 = tile << 4;
    const int row = r0 + m;

    ffrag acc[8];
    #pragma unroll
    for (int u = 0; u < 8; ++u)
        #pragma unroll
        for (int r = 0; r < 4; ++r) acc[u][r] = 0.f;

    const float* arow = cf + (size_t)row * DIN + quad * 8;
    #pragma unroll
    for (int kt = 0; kt < 6; ++kt) {
        float4 f0 = *(const float4*)(arow + kt * 32);
        float4 f1 = *(const float4*)(arow + kt * 32 + 4);
        bfrag a;
        a[0]=f2bf(f0.x); a[1]=f2bf(f0.y); a[2]=f2bf(f0.z); a[3]=f2bf(f0.w);
        a[4]=f2bf(f1.x); a[5]=f2bf(f1.y); a[6]=f2bf(f1.z); a[7]=f2bf(f1.w);
        #pragma unroll
        for (int u = 0; u < 8; ++u) {
            bfrag b = *(const bfrag*)(&Wl[(((kt * 8 + u) * 64 + lane) << 3)]);
            acc[u] = __builtin_amdgcn_mfma_f32_16x16x32_bf16(a, b, acc[u], 0, 0, 0);
        }
    }

    float mxu[8];
    #pragma unroll
    for (int u = 0; u < 8; ++u) mxu[u] = 0.f;

    #pragma unroll
    for (int r = 0; r < 4; ++r) {
        int er = r0 + quad * 4 + r;
        float exv = exists[er];
        __bf16* orow = xA + (size_t)er * HID;
        #pragma unroll
        for (int u = 0; u < 8; ++u) {
            int col = u * 16 + m;
            float v = fmaxf(acc[u][r] + bl[col], 0.f) * exv;
            orow[col] = f2bf(v);
            mxu[u] = fmaxf(mxu[u], v);
        }
    }
    #pragma unroll
    for (int u = 0; u < 8; ++u) {
        float v = mxu[u];
        v = fmaxf(v, __shfl_xor(v, 16));
        v = fmaxf(v, __shfl_xor(v, 32));
        if (quad == 0) atomicMax(&cm[u * 16 + m], __float_as_uint(v));
    }
    __syncthreads();
    if (t < HID) atomicMax(&pmax[t], cm[t]);
}

// ---------------------------------------------------------------------------
// Scan: 2 kernels.
// ---------------------------------------------------------------------------
__global__ __launch_bounds__(256) void k_scan1(
    const int* __restrict__ deg, int* __restrict__ bsum)
{
    const int b = blockIdx.x, t = threadIdx.x;
    int v = deg[b * 256 + t];
    #pragma unroll
    for (int o = 1; o < 64; o <<= 1) v += __shfl_xor(v, o);
    __shared__ int ws[4];
    if ((t & 63) == 0) ws[t >> 6] = v;
    __syncthreads();
    if (t == 0) bsum[b] = ws[0] + ws[1] + ws[2] + ws[3];
}

__global__ __launch_bounds__(256) void k_scan23(
    const int* __restrict__ deg, const int* __restrict__ bsum,
    int* __restrict__ off, int* __restrict__ cursor)
{
    __shared__ int sb[256], sc[256];
    const int b = blockIdx.x, t = threadIdx.x;
    int w = bsum[t];
    int v = deg[b * 256 + t];
    sb[t] = w; sc[t] = v;
    __syncthreads();
    for (int o = 1; o < 256; o <<= 1) {
        int u1 = (t >= o) ? sb[t - o] : 0;
        int u2 = (t >= o) ? sc[t - o] : 0;
        __syncthreads();
        sb[t] += u1; sc[t] += u2;
        __syncthreads();
    }
    int bbase = (b == 0) ? 0 : sb[b - 1];
    int excl = bbase + sc[t] - v;
    off[b * 256 + t] = excl;
    cursor[b * 256 + t] = excl;
    if (b == 255 && t == 255) off[NCH] = excl + v;
}

// ---------------------------------------------------------------------------
// Merged kernel: blocks 0..1023 = src projections, blocks 1024..5119 = scatter.
//   St2[n] = bf16( x[n] @ We[0:128] + be )    (frag-ordered)
//   Dq[n]  = fp8e4m3( x[n] @ We[128:256] )    permuted 32B-contiguous layout
// ---------------------------------------------------------------------------
__global__ __launch_bounds__(256) void k_scsrc(
    const __bf16* __restrict__ xCur, const float* __restrict__ We,
    const float* __restrict__ be, __bf16* __restrict__ St2,
    unsigned char* __restrict__ Dq,
    const int* __restrict__ eidx, int* __restrict__ cursor,
    const float* __restrict__ ef,
    int* __restrict__ dsts, unsigned char* __restrict__ efs8)
{
    __shared__ __bf16 Wl[4 * 8 * 64 * 8];   // 32 KB, reused for src then dst
    __shared__ float  bl[HID];
    const int t = threadIdx.x;

    if (blockIdx.x >= 1024) {
        // ---- scatter ----
        int e = (blockIdx.x - 1024) * 256 + t;
        int s = eidx[2 * e], d = eidx[2 * e + 1];
        const float4* p = (const float4*)(ef + (size_t)e * 8);
        float4 f0 = p[0], f1 = p[1];
        int pos = atomicAdd(&cursor[s], 1);
        dsts[pos] = d;
        unsigned p01 = __builtin_amdgcn_cvt_pk_fp8_f32(f0.x, f0.y, 0, false) & 0xffff;
        unsigned p23 = __builtin_amdgcn_cvt_pk_fp8_f32(f0.z, f0.w, 0, false) & 0xffff;
        unsigned p45 = __builtin_amdgcn_cvt_pk_fp8_f32(f1.x, f1.y, 0, false) & 0xffff;
        unsigned p67 = __builtin_amdgcn_cvt_pk_fp8_f32(f1.z, f1.w, 0, false) & 0xffff;
        unsigned long long v = (unsigned long long)(p01 | (p23 << 16))
                             | ((unsigned long long)(p45 | (p67 << 16)) << 32);
        *(unsigned long long*)(efs8 + (size_t)pos * 8) = v;
        return;
    }

    // ---- src ----
    const int wave = t >> 6, lane = t & 63;
    const int m = lane & 15, quad = lane >> 4;
    const int tile = blockIdx.x * 4 + wave;   // 1024 blocks -> 4096 tiles
    const int r0 = tile << 4;
    const int row = r0 + m;

    // phase 1: W_src
    stage_wfrag(Wl, We, 0, 2048, t);
    for (int idx = t; idx < HID; idx += 256) bl[idx] = be[idx];
    __syncthreads();

    bfrag a[4];
    const __bf16* ar = xCur + (size_t)row * HID + quad * 8;
    #pragma unroll
    for (int kt = 0; kt < 4; ++kt) a[kt] = *(const bfrag*)(ar + kt * 32);

    ffrag acc[8];
    #pragma unroll
    for (int u = 0; u < 8; ++u)
        #pragma unroll
        for (int r = 0; r < 4; ++r) acc[u][r] = 0.f;

    #pragma unroll
    for (int kt = 0; kt < 4; ++kt)
        #pragma unroll
        for (int u = 0; u < 8; ++u) {
            bfrag b = *(const bfrag*)(&Wl[(((kt * 8 + u) * 64 + lane) << 3)]);
            acc[u] = __builtin_amdgcn_mfma_f32_16x16x32_bf16(a[kt], b, acc[u], 0, 0, 0);
        }
    #pragma unroll
    for (int r = 0; r < 4; ++r) {
        int node = r0 + quad * 4 + r;
        bfrag pk;
        #pragma unroll
        for (int u = 0; u < 8; ++u) pk[u] = f2bf(acc[u][r] + bl[u * 16 + m]);
        *(bfrag*)(St2 + ((size_t)node * 16 + m) * 8) = pk;   // 16B coalesced
    }
    __syncthreads();   // all waves done reading Wl(src)

    // phase 2: W_dst (rows 128..255)
    stage_wfrag(Wl, We, 128, 2048, t);
    __syncthreads();

    #pragma unroll
    for (int u = 0; u < 8; ++u)
        #pragma unroll
        for (int r = 0; r < 4; ++r) acc[u][r] = 0.f;

    #pragma unroll
    for (int kt = 0; kt < 4; ++kt)
        #pragma unroll
        for (int u = 0; u < 8; ++u) {
            bfrag b = *(const bfrag*)(&Wl[(((kt * 8 + u) * 64 + lane) << 3)]);
            acc[u] = __builtin_amdgcn_mfma_f32_16x16x32_bf16(a[kt], b, acc[u], 0, 0, 0);
        }
    // D written PERMUTED compact fp8, NO bias
    #pragma unroll
    for (int r = 0; r < 4; ++r) {
        int node = r0 + quad * 4 + r;
        unsigned char* orow = Dq + (size_t)node * 128;
        #pragma unroll
        for (int u = 0; u < 8; ++u)
            orow[((u & 1) * 2 + (m >> 3)) * 32 + (u >> 1) * 8 + (m & 7)] = f2q(acc[u][r]);
    }
}

// ---------------------------------------------------------------------------
// Fused edge pass + segment_sum + col-max.
// R9: 2-deep gather pipeline (A0 compute / A1 arriving / A2 issued) — viable
// now that fp8+32B layout halved per-tile request pressure vs R5's null.
// Parent head fused via last-block trick on stage 2 (saves a dispatch).
// ---------------------------------------------------------------------------
__global__ __launch_bounds__(256) void k_edge2(
    const unsigned char* __restrict__ Dq,    // fp8 D rows, permuted, 128 B each
    const int*    __restrict__ offs,
    const int*    __restrict__ dsts,
    const unsigned char* __restrict__ efs8,  // fp8 ef, 8 B per edge
    const __bf16* __restrict__ St2,
    const float*  __restrict__ We,    // 264x128 slice; rows 256..263 used
    __bf16* __restrict__ xNext,
    unsigned int* __restrict__ pmax, int stage,
    const float* __restrict__ Wp, const float* __restrict__ bp,
    float* __restrict__ out, unsigned int* __restrict__ ctr)
{
    __shared__ unsigned char Wf[8 * 16 * 8];   // 1 KB: compact fp8 ef weights
    __shared__ unsigned int cm[HID];
    const int t = threadIdx.x;

    if (t < HID) cm[t] = 0u;
    // ef rows 256..263, compact fp8: [u][ln<16][j]
    for (int idx = t; idx < 8 * HID; idx += 256) {
        int k2 = idx >> 7, h = idx & 127;
        Wf[((((h >> 4) * 16) + (h & 15)) << 3) + k2] = f2q(We[(size_t)(256 + k2) * HID + h]);
    }
    __syncthreads();

    const int wave = t >> 6, lane = t & 63;
    const int m = lane & 15, quad = lane >> 4;
    const int gw = blockIdx.x * 4 + wave;    // grid 4096 -> 16384 waves
    const int n0 = gw * 4;                   // 4 nodes per wave, consecutive

    // fp8 one-hot identity B-fragments (e4m3 1.0 = 0x38)
    const long BevQ = (quad == (m >> 3))     ? ((long)0x38 << (8 * (m & 7))) : 0L;
    const long BodQ = (quad == 2 + (m >> 3)) ? ((long)0x38 << (8 * (m & 7))) : 0L;

    const int o0 = offs[n0],     o1 = offs[n0 + 1], o2 = offs[n0 + 2];
    const int o3 = offs[n0 + 3], o4 = offs[n0 + 4];

    auto selo = [&](int q) -> int {
        return (q <= 0) ? o0 : (q == 1) ? o1 : (q == 2) ? o2 : (q == 3) ? o3 : o4;
    };

    float mxu[8];
    #pragma unroll
    for (int u = 0; u < 8; ++u) mxu[u] = 0.f;

    if (o0 < o4) {
        const int dvA = dsts[min(o0 + lane, o4 - 1)];
        const int dvB = dsts[min(o0 + 64 + lane, o4 - 1)];

        auto LOADT = [&](int j) -> FragsQ {
            FragsQ f;
            int jl = j + m; jl = (jl < o4) ? jl : (o4 - 1);
            int rel = jl - o0;
            int dA = __shfl(dvA, rel & 63);
            int dB = __shfl(dvB, rel & 63);
            int dm;
            if (rel < 64)       dm = dA;
            else if (rel < 128) dm = dB;
            else                dm = dsts[jl];      // ultra-rare fallback
            const unsigned char* rd = Dq + (size_t)dm * 128 + quad * 32;
            lfrag2 w0 = *(const lfrag2*)(rd);
            lfrag2 w1 = *(const lfrag2*)(rd + 16);
            f.d[0] = w0[0]; f.d[1] = w0[1]; f.d[2] = w1[0]; f.d[3] = w1[1];
            f.ef = (quad == 0) ? *(const long*)(efs8 + (size_t)jl * 8) : 0L;
            return f;
        };

        // advance (i,j) -> next tile position; io=4 when exhausted
        auto adv = [&](int i, int j, int& io, int& jo) {
            int cEnd = selo(i + 1);
            int j2 = j + 16;
            if (j2 < cEnd) { io = i; jo = j2; return; }
            int i2 = i + 1;
            while (i2 < 4 && selo(i2) == selo(i2 + 1)) ++i2;
            io = i2; jo = (i2 < 4) ? selo(i2) : 0;
        };

        int i0 = 0;
        while (selo(i0) == selo(i0 + 1)) ++i0;   // first non-empty node
        int j0 = selo(i0);
        int i1, j1;
        adv(i0, j0, i1, j1);

        FragsQ A0 = LOADT(j0);
        FragsQ A1;
        if (i1 < 4) A1 = LOADT(j1);

        bfrag sb = *(const bfrag*)(St2 + ((size_t)(n0 + i0) * 16 + m) * 8);
        float part[8];
        #pragma unroll
        for (int u = 0; u < 8; ++u) part[u] = 0.f;

        for (;;) {
            int i2 = 4, j2 = 0;
            if (i1 < 4) adv(i1, j1, i2, j2);
            FragsQ A2;
            if (i2 < 4) A2 = LOADT(j2);         // 2-deep prefetch

            const int cEnd = selo(i0 + 1);
            ffrag acc[8];
            #pragma unroll
            for (int u = 0; u < 8; ++u) {
                float s = (float)sb[u];
                acc[u][0] = s; acc[u][1] = s; acc[u][2] = s; acc[u][3] = s;
            }
            // identity transpose: fp8 D rows -> C-layout
            #pragma unroll
            for (int u = 0; u < 8; ++u)
                acc[u] = __builtin_amdgcn_mfma_f32_16x16x32_fp8_fp8(
                    A0.d[u >> 1], (u & 1) ? BodQ : BevQ, acc[u], 0, 0, 0);
            // ef projection (fp8 x fp8)
            #pragma unroll
            for (int u = 0; u < 8; ++u) {
                long b = *(const long*)(&Wf[((u << 4) + m) << 3]);
                acc[u] = __builtin_amdgcn_mfma_f32_16x16x32_fp8_fp8(A0.ef, b, acc[u], 0, 0, 0);
            }

            const int rb = j0 + quad * 4;
            #pragma unroll
            for (int r = 0; r < 4; ++r) {
                if (rb + r < cEnd) {
                    #pragma unroll
                    for (int u = 0; u < 8; ++u)
                        part[u] += fmaxf(acc[u][r], 0.f);
                }
            }

            if (i1 >= 4 || i1 != i0) {
                float tot[8];
                #pragma unroll
                for (int u = 0; u < 8; ++u) {
                    float v = part[u];
                    v += __shfl_xor(v, 16);
                    v += __shfl_xor(v, 32);
                    tot[u] = v;
                    mxu[u] = fmaxf(mxu[u], v);
                }
                float sA = (quad == 0) ? tot[0] : (quad == 1) ? tot[2] : (quad == 2) ? tot[4] : tot[6];
                float sB = (quad == 0) ? tot[1] : (quad == 1) ? tot[3] : (quad == 2) ? tot[5] : tot[7];
                const int n = n0 + i0, u0 = quad * 2;
                xNext[(size_t)n * HID + u0 * 16 + m]      = f2bf(sA);
                xNext[(size_t)n * HID + u0 * 16 + 16 + m] = f2bf(sB);
                if (i1 < 4) {
                    sb = *(const bfrag*)(St2 + ((size_t)(n0 + i1) * 16 + m) * 8);
                    #pragma unroll
                    for (int u = 0; u < 8; ++u) part[u] = 0.f;
                }
            }
            if (i1 >= 4) break;
            A0 = A1; A1 = A2;
            i0 = i1; j0 = j1; i1 = i2; j1 = j2;
        }
    }

    // zero rows for empty nodes
    {
        const int u0 = quad * 2;
        const __bf16 zz = (__bf16)0.f;
        if (o0 == o1) { xNext[(size_t)(n0+0)*HID + u0*16 + m] = zz; xNext[(size_t)(n0+0)*HID + u0*16 + 16 + m] = zz; }
        if (o1 == o2) { xNext[(size_t)(n0+1)*HID + u0*16 + m] = zz; xNext[(size_t)(n0+1)*HID + u0*16 + 16 + m] = zz; }
        if (o2 == o3) { xNext[(size_t)(n0+2)*HID + u0*16 + m] = zz; xNext[(size_t)(n0+2)*HID + u0*16 + 16 + m] = zz; }
        if (o3 == o4) { xNext[(size_t)(n0+3)*HID + u0*16 + m] = zz; xNext[(size_t)(n0+3)*HID + u0*16 + 16 + m] = zz; }
    }

    #pragma unroll
    for (int u = 0; u < 8; ++u) {
        float v = mxu[u];
        v = fmaxf(v, __shfl_xor(v, 16));
        v = fmaxf(v, __shfl_xor(v, 32));
        if (quad == 0) atomicMax(&cm[u * 16 + m], __float_as_uint(v));
    }
    __syncthreads();
    if (t < HID) atomicMax(&pmax[stage * HID + t], cm[t]);

    // ---- stage 2: last block computes the parent head (saves a dispatch) ----
    if (stage == 2) {
        __syncthreads();                    // drain this block's pmax atomics
        __shared__ unsigned int done;
        if (t == 0) {
            __threadfence();                // order pmax atomics before ctr
            done = atomicAdd(ctr, 1u);
        }
        __syncthreads();
        if (done == gridDim.x - 1) {
            __shared__ float pl[384];
            for (int i = t; i < 384; i += 256)
                pl[i] = __uint_as_float(atomicOr(&pmax[i], 0u));   // coherent read
            __syncthreads();
            if (t < 128) {
                float acc2 = bp[t];
                for (int j = 0; j < 384; ++j) acc2 += pl[j] * Wp[j * HID + t];
                out[t] = fmaxf(acc2, 0.f);
            }
        }
    }
}

// ---------------------------------------------------------------------------
// Fallback path kernels (R1-proven, 48 MB footprint)
// ---------------------------------------------------------------------------
__global__ __launch_bounds__(256) void k_edge_at(
    const __bf16* __restrict__ xA, const int* __restrict__ eidx,
    const float* __restrict__ ef, const float* __restrict__ We,
    const float* __restrict__ be, float* __restrict__ xNew)
{
    __shared__ __bf16 Wl[9 * 8 * 64 * 8];
    __shared__ float  bl[HID];
    const int t = threadIdx.x;
    for (int idx = t; idx < 8 * 64 * 8; idx += 256) Wl[8 * 8 * 64 * 8 + idx] = (__bf16)0.f;
    __syncthreads();
    stage_wfrag(Wl, We, 0, 4096, t);   // 256*128/8 chunks
    for (int idx = t; idx < 8 * HID; idx += 256) {
        int k2 = idx >> 7, h = idx & 127;
        Wl[((((8 * 8) + (h >> 4)) * 64 + (h & 15)) << 3) | k2] = f2bf(We[(256 + k2) * HID + h]);
    }
    for (int idx = t; idx < HID; idx += 256) bl[idx] = be[idx];
    __syncthreads();

    const int wave = t >> 6, lane = t & 63;
    const int m = lane & 15, quad = lane >> 4;
    for (int c = 0; c < 8; ++c) {
        const int e0 = blockIdx.x * 512 + c * 64 + wave * 16;
        const int e  = e0 + m;
        const int src = eidx[2 * e], dst = eidx[2 * e + 1];
        const __bf16* rs = xA + (size_t)src * HID;
        const __bf16* rd = xA + (size_t)dst * HID;
        bfrag a[9];
        #pragma unroll
        for (int kt = 0; kt < 4; ++kt) a[kt] = *(const bfrag*)(rs + kt * 32 + quad * 8);
        #pragma unroll
        for (int kt = 4; kt < 8; ++kt) a[kt] = *(const bfrag*)(rd + (kt - 4) * 32 + quad * 8);
        {
            bfrag z;
            #pragma unroll
            for (int q = 0; q < 8; ++q) z[q] = (__bf16)0.f;
            if (quad == 0) {
                const float4* p = (const float4*)(ef + (size_t)e * 8);
                float4 f0 = p[0], f1 = p[1];
                z[0]=f2bf(f0.x); z[1]=f2bf(f0.y); z[2]=f2bf(f0.z); z[3]=f2bf(f0.w);
                z[4]=f2bf(f1.x); z[5]=f2bf(f1.y); z[6]=f2bf(f1.z); z[7]=f2bf(f1.w);
            }
            a[8] = z;
        }
        ffrag acc[8];
        #pragma unroll
        for (int u = 0; u < 8; ++u)
            #pragma unroll
            for (int r = 0; r < 4; ++r) acc[u][r] = 0.f;
        #pragma unroll
        for (int kt = 0; kt < 9; ++kt)
            #pragma unroll
            for (int u = 0; u < 8; ++u) {
                bfrag b = *(const bfrag*)(&Wl[(((kt * 8 + u) * 64 + lane) << 3)]);
                acc[u] = __builtin_amdgcn_mfma_f32_16x16x32_bf16(a[kt], b, acc[u], 0, 0, 0);
            }
        #pragma unroll
        for (int r = 0; r < 4; ++r) {
            int er = e0 + quad * 4 + r;
            int sr = eidx[2 * er];
            float* outrow = xNew + (size_t)sr * HID;
            #pragma unroll
            for (int u = 0; u < 8; ++u) {
                int col = u * 16 + m;
                atomicAdd(outrow + col, fmaxf(acc[u][r] + bl[col], 0.f));
            }
        }
    }
}

__global__ __launch_bounds__(256) void k_fin(
    float* __restrict__ xNew, __bf16* __restrict__ xA,
    unsigned int* __restrict__ pmax, int stage, int flags)
{
    const int t = threadIdx.x;
    const size_t total  = (size_t)NCH * HID;
    const size_t stride = (size_t)gridDim.x * 256;
    float mx = 0.f;
    for (size_t i = (size_t)blockIdx.x * 256 + t; i < total; i += stride) {
        float v = xNew[i];
        mx = fmaxf(mx, v);
        if (flags & 1) xA[i] = f2bf(v);
        if (flags & 2) xNew[i] = 0.f;
    }
    __shared__ float red[256];
    red[t] = mx;
    __syncthreads();
    if (t < 128) {
        float v = fmaxf(red[t], red[t + 128]);
        atomicMax(&pmax[stage * HID + t], __float_as_uint(v));
    }
}

// ---------------------------------------------------------------------------
// Parent head (fallback path only)
// ---------------------------------------------------------------------------
__global__ __launch_bounds__(128) void k_parent(
    const unsigned int* __restrict__ pmaxU,
    const float* __restrict__ Wp, const float* __restrict__ bp,
    float* __restrict__ out)
{
    __shared__ float pl[384];
    const int t = threadIdx.x;
    for (int i = t; i < 384; i += 128) pl[i] = __uint_as_float(pmaxU[i]);
    __syncthreads();
    float acc = bp[t];
    for (int j = 0; j < 384; ++j) acc += pl[j] * Wp[j * HID + t];
    out[t] = fmaxf(acc, 0.f);
}

extern "C" void kernel_launch(void* const* d_in, const int* in_sizes, int n_in,
                              void* d_out, int out_size, void* d_ws, size_t ws_size,
                              hipStream_t stream)
{
    const float* cf   = (const float*)d_in[0];
    const float* ex   = (const float*)d_in[1];
    const float* ef   = (const float*)d_in[2];
    const int*   eidx = (const int*)d_in[3];
    const float* Wc   = (const float*)d_in[4];
    const float* bc   = (const float*)d_in[5];
    const float* We   = (const float*)d_in[6];
    const float* be   = (const float*)d_in[7];
    const float* Wp   = (const float*)d_in[8];
    const float* bp   = (const float*)d_in[9];
    float* out = (float*)d_out;

    char* ws = (char*)d_ws;

    // CSR-fused path layout (~69 MB).  deg/pmax/ctr ADJACENT -> one memset.
    const size_t OFF_XA   = 0;
    const size_t OFF_XB   = OFF_XA   + (size_t)NCH * HID * 2;   // +16 MB
    const size_t OFF_ST   = OFF_XB   + (size_t)NCH * HID * 2;   // +16 MB
    const size_t OFF_EFS  = OFF_ST   + (size_t)NCH * HID * 2;   // +16 MB
    const size_t OFF_DQ   = OFF_EFS  + (size_t)NE * 8;          // +8 MB (fp8 ef)
    const size_t OFF_DST  = OFF_DQ   + (size_t)NCH * 128;       // +8 MB (fp8 D)
    const size_t OFF_OFFS = OFF_DST  + (size_t)NE * 4;          // +4 MB
    const size_t OFF_DEG  = OFF_OFFS + 262400;
    const size_t OFF_PMAX = OFF_DEG  + 262144;                  // adjacent to deg
    const size_t OFF_CTR  = OFF_PMAX + 2048;                    // adjacent to pmax
    const size_t OFF_CUR  = OFF_CTR  + 64;
    const size_t OFF_BS   = OFF_CUR  + 262144;   // bsum[256]
    const size_t NEED     = OFF_BS   + 1024;

    if (ws_size >= NEED) {
        __bf16*        xA   = (__bf16*)(ws + OFF_XA);
        __bf16*        xB   = (__bf16*)(ws + OFF_XB);
        __bf16*        St2  = (__bf16*)(ws + OFF_ST);
        unsigned char* efs8 = (unsigned char*)(ws + OFF_EFS);
        unsigned char* Dq   = (unsigned char*)(ws + OFF_DQ);
        int*           dsts = (int*)   (ws + OFF_DST);
        int*           offs = (int*)   (ws + OFF_OFFS);
        int*           deg  = (int*)   (ws + OFF_DEG);
        int*           cur  = (int*)   (ws + OFF_CUR);
        unsigned int*  pmax = (unsigned int*)(ws + OFF_PMAX);
        unsigned int*  ctr  = (unsigned int*)(ws + OFF_CTR);
        int*           bsum = (int*)   (ws + OFF_BS);

        // one memset covers deg (256 KB) + pmax + ctr (adjacent)
        hipMemsetAsync(deg, 0, 262144 + 2048 + 64, stream);

        k_childhist<<<2048, 256, 0, stream>>>(cf, ex, Wc, bc, xA, pmax, eidx, deg);
        k_scan1  <<<256,  256, 0, stream>>>(deg, bsum);
        k_scan23 <<<256,  256, 0, stream>>>(deg, bsum, offs, cur);

        // merged: src(stage1) blocks 0..1023  ||  scatter blocks 1024..5119
        k_scsrc  <<<5120, 256, 0, stream>>>(xA, We, be, St2, Dq,
                                            eidx, cur, ef, dsts, efs8);
        k_edge2  <<<4096, 256, 0, stream>>>(Dq, offs, dsts, efs8, St2, We, xB, pmax, 1,
                                            Wp, bp, out, ctr);
        k_scsrc  <<<1024, 256, 0, stream>>>(xB, We + 264 * HID, be + HID, St2, Dq,
                                            eidx, cur, ef, dsts, efs8);   // src only
        k_edge2  <<<4096, 256, 0, stream>>>(Dq, offs, dsts, efs8, St2, We + 264 * HID, xA, pmax, 2,
                                            Wp, bp, out, ctr);            // + fused parent
    } else {
        // fallback: R1 atomic path (48 MB)
        float*        xNew = (float*)ws;
        __bf16*       xA   = (__bf16*)(ws + (size_t)NCH * HID * 4);
        unsigned int* pmax = (unsigned int*)(ws + (size_t)NCH * HID * 6);

        hipMemsetAsync(pmax, 0, 384 * sizeof(unsigned int), stream);
        hipMemsetAsync(xNew, 0, (size_t)NCH * HID * 4, stream);

        k_childhist<<<1024, 256, 0, stream>>>(cf, ex, Wc, bc, xA, pmax, eidx, (int*)nullptr);
        k_edge_at<<<2048, 256, 0, stream>>>(xA, eidx, ef, We,             be,       xNew);
        k_fin    <<<512,  256, 0, stream>>>(xNew, xA, pmax, 1, 3);
        k_edge_at<<<2048, 256, 0, stream>>>(xA, eidx, ef, We + 264 * HID, be + HID, xNew);
        k_fin    <<<512,  256, 0, stream>>>(xNew, xA, pmax, 2, 0);
        k_parent <<<1,    128, 0, stream>>>(pmax, Wp, bp, out);
    }
}